// Round 9
// baseline (622.205 us; speedup 1.0000x reference)
//
#include <hip/hip_runtime.h>
#include <hip/hip_cooperative_groups.h>
#include <cstdint>
#include <cstddef>

namespace cg = cooperative_groups;

#define NEG_SLOPE 0.2f
#define BIN_SHIFT 9      // 512 nodes per bucket
#define BCAP 16384       // fixed tmpE capacity per bucket (expected ~8700, ~80 sigma margin)
#define LOG2E 1.4426950408889634f

typedef short bf16x8 __attribute__((ext_vector_type(8)));
typedef float f32x4 __attribute__((ext_vector_type(4)));

#if __has_builtin(__builtin_amdgcn_exp2f)
#define EXP2(x) __builtin_amdgcn_exp2f(x)
#else
#define EXP2(x) exp2f(x)
#endif

// fp32 -> bf16 RTNE
static __device__ __forceinline__ unsigned short bf16r(float f) {
    unsigned u = __float_as_uint(f);
    return (unsigned short)((u + 0x7fffu + ((u >> 16) & 1u)) >> 16);
}
static __device__ __forceinline__ float bfu_lo(unsigned u) { return __uint_as_float(u << 16); }
static __device__ __forceinline__ float bfu_hi(unsigned u) { return __uint_as_float(u & 0xffff0000u); }

// ================= shared bodies =================

// W prep: one element of the bf16 hi/lo split into MFMA-fragment-contiguous layout.
static __device__ __forceinline__ void wprep_elem(int t, const float* W1, const float* W2,
                                                  unsigned short* Wh1, unsigned short* Wl1,
                                                  unsigned short* Wh2, unsigned short* Wl2) {
    const float* W;
    unsigned short *Wh, *Wl;
    int idx;
    if (t < 16384) { W = W1; Wh = Wh1; Wl = Wl1; idx = t; }
    else           { W = W2; Wh = Wh2; Wl = Wl2; idx = t - 16384; }
    int c = idx >> 7;     // output col 0..127
    int k = idx & 127;    // input k 0..127
    float w = W[(size_t)k * 128 + c];
    unsigned short h = bf16r(w);
    float lo = w - __uint_as_float((unsigned)h << 16);
    int dst = (k >> 5) * 4096 + (c >> 4) * 512 + (((k >> 3) & 3) * 16 + (c & 15)) * 8 + (k & 7);
    Wh[dst] = h;
    Wl[dst] = bf16r(lo);
}

// bin: one 4096-edge chunk into fixed-capacity dst buckets via LDS counting sort.
static __device__ void bin_body(int bid, const int* __restrict__ srcI, const int* __restrict__ dstI,
                                int E, int N, int K, int* __restrict__ bcnt, int* __restrict__ tmpE,
                                int* hist, int* lbase, int* lstart, int* cur, int* sc,
                                int* staged, unsigned char* bs) {
    const int t = threadIdx.x;
    const int M = E + N;
    const int chunk0 = bid * 4096;
    hist[t] = 0;
    __syncthreads();

    int pk[16], bk[16];
#pragma unroll
    for (int j = 0; j < 16; ++j) {
        int i = chunk0 + t + j * 256;
        bk[j] = -1;
        if (i < M) {
            int ss, dd;
            if (i < E) { ss = srcI[i]; dd = dstI[i]; }
            else       { ss = i - E;  dd = ss; }
            if ((unsigned)dd < (unsigned)N && (unsigned)ss < (unsigned)N) {
                bk[j] = dd >> BIN_SHIFT;
                pk[j] = (ss << 9) | (dd & 511);
                atomicAdd(&hist[bk[j]], 1);
            }
        }
    }
    __syncthreads();
    const int h = hist[t];
    lbase[t] = (h > 0) ? atomicAdd(&bcnt[t], h) : 0;
    sc[t] = h;
    __syncthreads();
    for (int off = 1; off < 256; off <<= 1) {
        int v = (t >= off) ? sc[t - off] : 0;
        __syncthreads();
        sc[t] += v;
        __syncthreads();
    }
    lstart[t] = sc[t] - h;
    cur[t]    = sc[t] - h;
    __syncthreads();
#pragma unroll
    for (int j = 0; j < 16; ++j) {
        if (bk[j] >= 0) {
            int r = atomicAdd(&cur[bk[j]], 1);
            staged[r] = pk[j];
            bs[r] = (unsigned char)bk[j];
        }
    }
    const int total = sc[255];
    __syncthreads();
    for (int s = t; s < total; s += 256) {
        int b = bs[s];
        int posInBucket = lbase[b] + (s - lstart[b]);
        if (posInBucket < BCAP) tmpE[(size_t)b * BCAP + posInBucket] = staged[s];
    }
    __syncthreads();   // LDS reused by next chunk / next phase
}

// scatter: one bucket -> local CSR build + dense scatter; colOff = src*256 byte offsets.
static __device__ void scatter_body(int b, const int* __restrict__ tmpE, const int* __restrict__ bcnt,
                                    int* __restrict__ rowptr, int* __restrict__ colOff,
                                    int N, int K, int* pre, int* cur, int* ss) {
    const int t = threadIdx.x;

    int bc = (t < K) ? min(bcnt[t], BCAP) : 0;
    pre[t] = bc;
    __syncthreads();
    for (int off = 1; off < 256; off <<= 1) {
        int v = (t >= off) ? pre[t - off] : 0;
        __syncthreads();
        pre[t] += v;
        __syncthreads();
    }
    const int base_b = (b == 0) ? 0 : pre[b - 1];
    const int cnt_b  = pre[b] - base_b;
    if (b == K - 1 && t == 0) rowptr[N] = pre[K - 1];

    const int nlo = b << BIN_SHIFT;
    const int nhi = min(nlo + (1 << BIN_SHIFT), N);
    const int nn  = nhi - nlo;
    const int* te = tmpE + (size_t)b * BCAP;

    cur[t] = 0;
    cur[t + 256] = 0;
    __syncthreads();
    for (int i = t; i < cnt_b; i += 256) atomicAdd(&cur[te[i] & 511], 1);
    __syncthreads();

    int v0 = cur[2 * t], v1 = cur[2 * t + 1];
    ss[t] = v0 + v1;
    __syncthreads();
    for (int off = 1; off < 256; off <<= 1) {
        int v = (t >= off) ? ss[t - off] : 0;
        __syncthreads();
        ss[t] += v;
        __syncthreads();
    }
    int e0 = (t == 0) ? 0 : ss[t - 1];
    int e1 = e0 + v0;
    if (2 * t < nn)     rowptr[nlo + 2 * t]     = base_b + e0;
    if (2 * t + 1 < nn) rowptr[nlo + 2 * t + 1] = base_b + e1;
    cur[2 * t] = e0;
    cur[2 * t + 1] = e1;
    __syncthreads();

    for (int i = t; i < cnt_b; i += 256) {
        int v = te[i];
        int r = atomicAdd(&cur[v & 511], 1);
        colOff[base_b + r] = ((unsigned)v >> 9) << 8;
    }
    __syncthreads();   // LDS reused by next bucket
}

// gemm: one 128-row tile of h = X @ W via split-bf16 MFMA; bf16 Hout + log2e-scaled fp32 alphas.
static __device__ void gemm_body(int bid, const float* __restrict__ X,
                                 const unsigned short* __restrict__ Wh,
                                 const unsigned short* __restrict__ Wl,
                                 const float* __restrict__ a_s,
                                 const float* __restrict__ a_d,
                                 unsigned short* __restrict__ Hout,
                                 float* __restrict__ asrc,
                                 float* __restrict__ adst,
                                 int N, unsigned short* hstage) {
    const int tid = threadIdx.x;
    const int wid = tid >> 6;
    const int l   = tid & 63;
    const int l15 = l & 15;
    const int lh  = l >> 4;
    const int waveRow = bid * 128 + wid * 32;
    if (waveRow >= N) return;

    f32x4 acc[2][8];
#pragma unroll
    for (int m = 0; m < 2; ++m)
#pragma unroll
        for (int f = 0; f < 8; ++f)
#pragma unroll
            for (int c = 0; c < 4; ++c) acc[m][f][c] = 0.f;

    const int r0 = waveRow + l15;
    const int r1 = waveRow + 16 + l15;
    const size_t xoff0 = (size_t)min(r0, N - 1) * 128;   // clamp: junk rows never stored
    const size_t xoff1 = (size_t)min(r1, N - 1) * 128;
    const int kb = lh * 8;

#pragma unroll
    for (int ks = 0; ks < 4; ++ks) {
        bf16x8 ah[2], al[2];
#pragma unroll
        for (int m = 0; m < 2; ++m) {
            const float* xp = X + (m ? xoff1 : xoff0) + ks * 32 + kb;
            float4 v0 = *(const float4*)xp;
            float4 v1 = *(const float4*)(xp + 4);
            float xs[8] = {v0.x, v0.y, v0.z, v0.w, v1.x, v1.y, v1.z, v1.w};
#pragma unroll
            for (int j = 0; j < 8; ++j) {
                unsigned short h = bf16r(xs[j]);
                float hf = __uint_as_float((unsigned)h << 16);
                ah[m][j] = (short)h;
                al[m][j] = (short)bf16r(xs[j] - hf);
            }
        }
        const unsigned short* wbh = Wh + ks * 4096 + l * 8;
        const unsigned short* wbl = Wl + ks * 4096 + l * 8;
#pragma unroll
        for (int f = 0; f < 8; ++f) {
            bf16x8 wh = *(const bf16x8*)(wbh + f * 512);
            bf16x8 wl = *(const bf16x8*)(wbl + f * 512);
#pragma unroll
            for (int m = 0; m < 2; ++m) {
                acc[m][f] = __builtin_amdgcn_mfma_f32_16x16x32_bf16(ah[m], wh, acc[m][f], 0, 0, 0);
                acc[m][f] = __builtin_amdgcn_mfma_f32_16x16x32_bf16(al[m], wh, acc[m][f], 0, 0, 0);
                acc[m][f] = __builtin_amdgcn_mfma_f32_16x16x32_bf16(ah[m], wl, acc[m][f], 0, 0, 0);
            }
        }
    }

    float asf[8], adf[8];
#pragma unroll
    for (int f = 0; f < 8; ++f) {
        asf[f] = a_s[f * 16 + l15];
        adf[f] = a_d[f * 16 + l15];
    }
    const int q = l15;
#pragma unroll
    for (int m = 0; m < 2; ++m) {
#pragma unroll
        for (int r = 0; r < 4; ++r) {
            float ps[4] = {0.f, 0.f, 0.f, 0.f};
            float pd[4] = {0.f, 0.f, 0.f, 0.f};
#pragma unroll
            for (int f = 0; f < 8; ++f) {
                float v = acc[m][f][r];
                ps[f >> 1] = fmaf(v, asf[f], ps[f >> 1]);
                pd[f >> 1] = fmaf(v, adf[f], pd[f >> 1]);
                hstage[((wid * 32) + m * 16 + lh * 4 + r) * 132 + f * 16 + l15] = bf16r(v);
            }
#pragma unroll
            for (int mask = 1; mask < 16; mask <<= 1) {
#pragma unroll
                for (int h = 0; h < 4; ++h) {
                    ps[h] += __shfl_xor(ps[h], mask);
                    pd[h] += __shfl_xor(pd[h], mask);
                }
            }
            int row = waveRow + m * 16 + lh * 4 + r;
            if (q < 8 && row < N) {
                float v0 = (q & 1) ? ps[1] : ps[0];
                float v1 = (q & 1) ? ps[3] : ps[2];
                float vs = (q & 2) ? v1 : v0;
                float w0 = (q & 1) ? pd[1] : pd[0];
                float w1 = (q & 1) ? pd[3] : pd[2];
                float vd = (q & 2) ? w1 : w0;
                // pre-scale by log2(e): aggregate uses native exp2 (lrelu is pos-homogeneous)
                if (q < 4) asrc[row * 4 + q] = vs * LOG2E;
                else       adst[row * 4 + (q - 4)] = vd * LOG2E;
            }
        }
    }

    // coalesced bf16 store: 16 lanes cover one 256B h-row, 4 rows per iteration
#pragma unroll
    for (int it = 0; it < 8; ++it) {
        int row = it * 4 + lh;
        const unsigned short* hp = hstage + ((wid * 32) + row) * 132 + l15 * 8;
        uint2 aa = *(const uint2*)hp;
        uint2 bb = *(const uint2*)(hp + 4);
        int grow = waveRow + row;
        if (grow < N) {
            uint4 o;
            o.x = aa.x; o.y = aa.y; o.z = bb.x; o.w = bb.y;
            *(uint4*)&Hout[(size_t)grow * 128 + l15 * 8] = o;
        }
    }
}

// aggregate: 4 nodes per block (one wave each); all-8-wide predicated chunks (tail lanes w=0 exact).
static __device__ void agg_body(int grp, const unsigned short* __restrict__ Hbuf,
                                const float* __restrict__ asrc, const float* __restrict__ adst,
                                const int* __restrict__ rowptr, const int* __restrict__ colOff,
                                const float* __restrict__ bias, float* __restrict__ out, int N) {
    const int wid  = threadIdx.x >> 6;
    const int lane = threadIdx.x & 63;
    const int n = grp * 4 + wid;
    if (n >= N) return;
    const int c0 = lane * 2;
    const int head = c0 >> 5;
    const float adh = adst[n * 4 + head];
    const char* Hb = (const char*)Hbuf;
    const char* As = (const char*)asrc;
    const int hoff = c0 * 2;
    const int aoff = head * 4;

    int b = __builtin_amdgcn_readfirstlane(rowptr[n]);
    int e = __builtin_amdgcn_readfirstlane(rowptr[n + 1]);
    float acc0 = 0.f, acc1 = 0.f, sw = 0.f;
    for (int p = b; p < e; p += 8) {
        int off[8];
#pragma unroll
        for (int j = 0; j < 8; ++j) off[j] = colOff[min(p + j, e - 1)];
        float a[8];
#pragma unroll
        for (int j = 0; j < 8; ++j) a[j] = *(const float*)(As + (off[j] >> 4) + aoff);
        unsigned hu[8];
#pragma unroll
        for (int j = 0; j < 8; ++j) hu[j] = *(const unsigned*)(Hb + off[j] + hoff);
#pragma unroll
        for (int j = 0; j < 8; ++j) {
            float x = a[j] + adh;
            float w = (p + j < e) ? EXP2(fmaxf(x, NEG_SLOPE * x)) : 0.f;
            sw += w;
            acc0 = fmaf(w, bfu_lo(hu[j]), acc0);
            acc1 = fmaf(w, bfu_hi(hu[j]), acc1);
        }
    }
    float inv = 1.f / sw;
    float o0 = fmaxf(acc0 * inv + bias[c0], 0.f);
    float o1 = fmaxf(acc1 * inv + bias[c0 + 1], 0.f);
    *(float2*)&out[(size_t)n * 128 + c0] = make_float2(o0, o1);
}

// ================= cooperative kernels =================

struct PrepArgs {
    const float *W1, *W2;
    unsigned short *Wh1, *Wl1, *Wh2, *Wl2;
    int* bcnt;
    const int *srcI, *dstI;
    int* tmpE;
    int *rowptr, *colOff;
    int E, N, K, nchunks;
};

__global__ __launch_bounds__(256) void prep_coop_k(PrepArgs a) {
    __shared__ int hist[256], lbase[256], lstart[256], curA[256], sc[256];
    __shared__ int staged[4096];
    __shared__ unsigned char bs[4096];
    __shared__ int pre[256], curB[512], ss[256];
    cg::grid_group grid = cg::this_grid();
    const int t = threadIdx.x;

    // phase 0: W pre-split + bcnt zeroing
    if (blockIdx.x == 0) a.bcnt[t] = 0;
    for (int i = blockIdx.x * 256 + t; i < 32768; i += gridDim.x * 256)
        wprep_elem(i, a.W1, a.W2, a.Wh1, a.Wl1, a.Wh2, a.Wl2);
    __threadfence();
    grid.sync();

    // phase 1: bin
    for (int c = blockIdx.x; c < a.nchunks; c += gridDim.x)
        bin_body(c, a.srcI, a.dstI, a.E, a.N, a.K, a.bcnt, a.tmpE,
                 hist, lbase, lstart, curA, sc, staged, bs);
    __threadfence();
    grid.sync();

    // phase 2: per-bucket CSR build + scatter
    for (int b = blockIdx.x; b < a.K; b += gridDim.x)
        scatter_body(b, a.tmpE, a.bcnt, a.rowptr, a.colOff, a.N, a.K, pre, curB, ss);
}

struct MainArgs {
    const float* X;
    const unsigned short *Wh1, *Wl1, *Wh2, *Wl2;
    const float *as1, *ad1, *b1, *as2, *ad2, *b2;
    unsigned short* Hbuf;
    float *asrc, *adst;
    const int *rowptr, *colOff;
    float* out;
    int N, gemmTiles, nodeGroups;
};

__global__ __launch_bounds__(256, 3) void main_coop_k(MainArgs a) {
    __shared__ __align__(16) unsigned short hstage[4 * 32 * 132];
    cg::grid_group grid = cg::this_grid();

    for (int tl = blockIdx.x; tl < a.gemmTiles; tl += gridDim.x)
        gemm_body(tl, a.X, a.Wh1, a.Wl1, a.as1, a.ad1, a.Hbuf, a.asrc, a.adst, a.N, hstage);
    __threadfence();
    grid.sync();
    for (int gp = blockIdx.x; gp < a.nodeGroups; gp += gridDim.x)
        agg_body(gp, a.Hbuf, a.asrc, a.adst, a.rowptr, a.colOff, a.b1, a.out, a.N);
    __threadfence();
    grid.sync();
    for (int tl = blockIdx.x; tl < a.gemmTiles; tl += gridDim.x)
        gemm_body(tl, a.out, a.Wh2, a.Wl2, a.as2, a.ad2, a.Hbuf, a.asrc, a.adst, a.N, hstage);
    __threadfence();
    grid.sync();
    for (int gp = blockIdx.x; gp < a.nodeGroups; gp += gridDim.x)
        agg_body(gp, a.Hbuf, a.asrc, a.adst, a.rowptr, a.colOff, a.b2, a.out, a.N);
}

// ================= fallback standalone kernels (R8-proven path) =================

__global__ __launch_bounds__(256) void wprep_k(const float* W1, const float* W2,
                                               unsigned short* Wh1, unsigned short* Wl1,
                                               unsigned short* Wh2, unsigned short* Wl2,
                                               int* bcnt) {
    if (blockIdx.x == 0) bcnt[threadIdx.x] = 0;
    int t = blockIdx.x * 256 + threadIdx.x;
    if (t < 32768) wprep_elem(t, W1, W2, Wh1, Wl1, Wh2, Wl2);
}

__global__ __launch_bounds__(256) void bin_k(const int* srcI, const int* dstI,
                                             int E, int N, int K, int* bcnt, int* tmpE) {
    __shared__ int hist[256], lbase[256], lstart[256], curA[256], sc[256];
    __shared__ int staged[4096];
    __shared__ unsigned char bs[4096];
    bin_body(blockIdx.x, srcI, dstI, E, N, K, bcnt, tmpE, hist, lbase, lstart, curA, sc, staged, bs);
}

__global__ __launch_bounds__(256) void scatter_csr_k(const int* tmpE, const int* bcnt,
                                                     int* rowptr, int* colOff, int N, int K) {
    __shared__ int pre[256], curB[512], ss[256];
    scatter_body(blockIdx.x, tmpE, bcnt, rowptr, colOff, N, K, pre, curB, ss);
}

__global__ __launch_bounds__(256) void gemm_mfma_k(const float* X, const unsigned short* Wh,
                                                   const unsigned short* Wl, const float* a_s,
                                                   const float* a_d, unsigned short* Hout,
                                                   float* asrc, float* adst, int N) {
    __shared__ __align__(16) unsigned short hstage[4 * 32 * 132];
    gemm_body(blockIdx.x, X, Wh, Wl, a_s, a_d, Hout, asrc, adst, N, hstage);
}

__global__ __launch_bounds__(256) void aggregate_k(const unsigned short* Hbuf, const float* asrc,
                                                   const float* adst, const int* rowptr,
                                                   const int* colOff, const float* bias,
                                                   float* out, int N) {
    agg_body(blockIdx.x, Hbuf, asrc, adst, rowptr, colOff, bias, out, N);
}

// ================= launch =================

extern "C" void kernel_launch(void* const* d_in, const int* in_sizes, int n_in,
                              void* d_out, int out_size, void* d_ws, size_t ws_size,
                              hipStream_t stream) {
    const float* X   = (const float*)d_in[0];
    const int*   EI  = (const int*)d_in[1];
    const float* W1  = (const float*)d_in[2];
    const float* as1 = (const float*)d_in[3];
    const float* ad1 = (const float*)d_in[4];
    const float* b1  = (const float*)d_in[5];
    const float* W2  = (const float*)d_in[6];
    const float* as2 = (const float*)d_in[7];
    const float* ad2 = (const float*)d_in[8];
    const float* b2  = (const float*)d_in[9];

    const int N = in_sizes[0] / 128;
    const int E = in_sizes[1] / 2;
    const int M = E + N;
    const int K = (N + (1 << BIN_SHIFT) - 1) >> BIN_SHIFT;   // <= 256 for N <= 131072
    const int* srcI = EI;
    const int* dstI = EI + E;

    char* w = (char*)d_ws;
    auto alloc = [&](size_t bytes) {
        char* p = w;
        w += (bytes + 255) & ~(size_t)255;
        return p;
    };
    unsigned short* Hbuf = (unsigned short*)alloc((size_t)N * 128 * 2);  // bf16, 256B rows
    float* asrc   = (float*)alloc((size_t)N * 4 * 4);
    float* adst   = (float*)alloc((size_t)N * 4 * 4);
    int*   rowptr = (int*)alloc((size_t)(N + 1) * 4);
    int*   colOff = (int*)alloc((size_t)M * 4);
    int*   tmpE   = (int*)alloc((size_t)K * BCAP * 4);       // packed (src<<9 | dst&511)
    int*   bcnt   = (int*)alloc(256 * 4);
    unsigned short* Wt1h = (unsigned short*)alloc(128 * 128 * 2);
    unsigned short* Wt1l = (unsigned short*)alloc(128 * 128 * 2);
    unsigned short* Wt2h = (unsigned short*)alloc(128 * 128 * 2);
    unsigned short* Wt2l = (unsigned short*)alloc(128 * 128 * 2);

    const int gemmTiles  = (N + 127) / 128;
    const int nodeGroups = (N + 3) / 4;
    const int nchunks    = (M + 4095) / 4096;
    float* out = (float*)d_out;

    // occupancy-driven cooperative grid sizes (cached after first call)
    static int s_numCU = 0, s_prepOcc = 0, s_mainOcc = 0;
    if (s_numCU == 0) {
        int dev = 0;
        hipDeviceProp_t props;
        if (hipGetDevice(&dev) == hipSuccess && hipGetDeviceProperties(&props, dev) == hipSuccess)
            s_numCU = props.multiProcessorCount;
        if (s_numCU <= 0) s_numCU = 256;
        if (hipOccupancyMaxActiveBlocksPerMultiprocessor(&s_prepOcc, prep_coop_k, 256, 0) != hipSuccess)
            s_prepOcc = 0;
        if (hipOccupancyMaxActiveBlocksPerMultiprocessor(&s_mainOcc, main_coop_k, 256, 0) != hipSuccess)
            s_mainOcc = 0;
        (void)hipGetLastError();
    }

    bool prepDone = false, mainDone = false;

    if (s_prepOcc > 0) {
        int prepGrid = s_prepOcc * s_numCU;
        if (prepGrid > nchunks) prepGrid = nchunks;
        PrepArgs pa;
        pa.W1 = W1; pa.W2 = W2;
        pa.Wh1 = Wt1h; pa.Wl1 = Wt1l; pa.Wh2 = Wt2h; pa.Wl2 = Wt2l;
        pa.bcnt = bcnt; pa.srcI = srcI; pa.dstI = dstI; pa.tmpE = tmpE;
        pa.rowptr = rowptr; pa.colOff = colOff;
        pa.E = E; pa.N = N; pa.K = K; pa.nchunks = nchunks;
        void* pargs[] = { &pa };
        if (hipLaunchCooperativeKernel(prep_coop_k, dim3(prepGrid), dim3(256), pargs, 0, stream) == hipSuccess)
            prepDone = true;
        else
            (void)hipGetLastError();
    }
    if (!prepDone) {
        wprep_k<<<128, 256, 0, stream>>>(W1, W2, Wt1h, Wt1l, Wt2h, Wt2l, bcnt);
        bin_k<<<nchunks, 256, 0, stream>>>(srcI, dstI, E, N, K, bcnt, tmpE);
        scatter_csr_k<<<K, 256, 0, stream>>>(tmpE, bcnt, rowptr, colOff, N, K);
    }

    if (s_mainOcc > 0) {
        int mainGrid = s_mainOcc * s_numCU;
        if (mainGrid > nodeGroups) mainGrid = nodeGroups;
        MainArgs ma;
        ma.X = X;
        ma.Wh1 = Wt1h; ma.Wl1 = Wt1l; ma.Wh2 = Wt2h; ma.Wl2 = Wt2l;
        ma.as1 = as1; ma.ad1 = ad1; ma.b1 = b1;
        ma.as2 = as2; ma.ad2 = ad2; ma.b2 = b2;
        ma.Hbuf = Hbuf; ma.asrc = asrc; ma.adst = adst;
        ma.rowptr = rowptr; ma.colOff = colOff;
        ma.out = out;
        ma.N = N; ma.gemmTiles = gemmTiles; ma.nodeGroups = nodeGroups;
        void* margs[] = { &ma };
        if (hipLaunchCooperativeKernel(main_coop_k, dim3(mainGrid), dim3(256), margs, 0, stream) == hipSuccess)
            mainDone = true;
        else
            (void)hipGetLastError();
    }
    if (!mainDone) {
        gemm_mfma_k<<<gemmTiles, 256, 0, stream>>>(X, Wt1h, Wt1l, as1, ad1, Hbuf, asrc, adst, N);
        aggregate_k<<<nodeGroups, 256, 0, stream>>>(Hbuf, asrc, adst, rowptr, colOff, b1, out, N);
        gemm_mfma_k<<<gemmTiles, 256, 0, stream>>>(out, Wt2h, Wt2l, as2, ad2, Hbuf, asrc, adst, N);
        aggregate_k<<<nodeGroups, 256, 0, stream>>>(Hbuf, asrc, adst, rowptr, colOff, b2, out, N);
    }
}

// Round 10
// 405.505 us; speedup vs baseline: 1.5344x; 1.5344x over previous
//
#include <hip/hip_runtime.h>
#include <cstdint>
#include <cstddef>

#define NEG_SLOPE 0.2f
#define BIN_SHIFT 9      // 512 nodes per bucket
#define BCAP 16384       // fixed tmpE capacity per bucket (expected ~8700, ~80 sigma margin)
#define LOG2E 1.4426950408889634f

typedef short bf16x8 __attribute__((ext_vector_type(8)));
typedef float f32x4 __attribute__((ext_vector_type(4)));

#if __has_builtin(__builtin_amdgcn_exp2f)
#define EXP2(x) __builtin_amdgcn_exp2f(x)
#else
#define EXP2(x) exp2f(x)
#endif

// fp32 -> bf16 RTNE
static __device__ __forceinline__ unsigned short bf16r(float f) {
    unsigned u = __float_as_uint(f);
    return (unsigned short)((u + 0x7fffu + ((u >> 16) & 1u)) >> 16);
}
static __device__ __forceinline__ float bfu_lo(unsigned u) { return __uint_as_float(u << 16); }
static __device__ __forceinline__ float bfu_hi(unsigned u) { return __uint_as_float(u & 0xffff0000u); }

// ================= shared bodies (byte-identical numerics to R8) =================

// W prep: one element of the bf16 hi/lo split into MFMA-fragment-contiguous layout.
static __device__ __forceinline__ void wprep_elem(int t, const float* W1, const float* W2,
                                                  unsigned short* Wh1, unsigned short* Wl1,
                                                  unsigned short* Wh2, unsigned short* Wl2) {
    const float* W;
    unsigned short *Wh, *Wl;
    int idx;
    if (t < 16384) { W = W1; Wh = Wh1; Wl = Wl1; idx = t; }
    else           { W = W2; Wh = Wh2; Wl = Wl2; idx = t - 16384; }
    int c = idx >> 7;     // output col 0..127
    int k = idx & 127;    // input k 0..127
    float w = W[(size_t)k * 128 + c];
    unsigned short h = bf16r(w);
    float lo = w - __uint_as_float((unsigned)h << 16);
    int dst = (k >> 5) * 4096 + (c >> 4) * 512 + (((k >> 3) & 3) * 16 + (c & 15)) * 8 + (k & 7);
    Wh[dst] = h;
    Wl[dst] = bf16r(lo);
}

// bin: one 4096-edge chunk into fixed-capacity dst buckets via LDS counting sort.
static __device__ void bin_body(int bid, const int* __restrict__ srcI, const int* __restrict__ dstI,
                                int E, int N, int K, int* __restrict__ bcnt, int* __restrict__ tmpE,
                                int* hist, int* lbase, int* lstart, int* cur, int* sc,
                                int* staged, unsigned char* bs) {
    const int t = threadIdx.x;
    const int M = E + N;
    const int chunk0 = bid * 4096;
    hist[t] = 0;
    __syncthreads();

    int pk[16], bk[16];
#pragma unroll
    for (int j = 0; j < 16; ++j) {
        int i = chunk0 + t + j * 256;
        bk[j] = -1;
        if (i < M) {
            int ss, dd;
            if (i < E) { ss = srcI[i]; dd = dstI[i]; }
            else       { ss = i - E;  dd = ss; }
            if ((unsigned)dd < (unsigned)N && (unsigned)ss < (unsigned)N) {
                bk[j] = dd >> BIN_SHIFT;
                pk[j] = (ss << 9) | (dd & 511);
                atomicAdd(&hist[bk[j]], 1);
            }
        }
    }
    __syncthreads();
    const int h = hist[t];
    lbase[t] = (h > 0) ? atomicAdd(&bcnt[t], h) : 0;
    sc[t] = h;
    __syncthreads();
    for (int off = 1; off < 256; off <<= 1) {
        int v = (t >= off) ? sc[t - off] : 0;
        __syncthreads();
        sc[t] += v;
        __syncthreads();
    }
    lstart[t] = sc[t] - h;
    cur[t]    = sc[t] - h;
    __syncthreads();
#pragma unroll
    for (int j = 0; j < 16; ++j) {
        if (bk[j] >= 0) {
            int r = atomicAdd(&cur[bk[j]], 1);
            staged[r] = pk[j];
            bs[r] = (unsigned char)bk[j];
        }
    }
    const int total = sc[255];
    __syncthreads();
    for (int s = t; s < total; s += 256) {
        int b = bs[s];
        int posInBucket = lbase[b] + (s - lstart[b]);
        if (posInBucket < BCAP) tmpE[(size_t)b * BCAP + posInBucket] = staged[s];
    }
}

// scatter: one bucket -> local CSR build + dense scatter; colOff = src*256 byte offsets.
static __device__ void scatter_body(int b, const int* __restrict__ tmpE, const int* __restrict__ bcnt,
                                    int* __restrict__ rowptr, int* __restrict__ colOff,
                                    int N, int K, int* pre, int* cur, int* ss) {
    const int t = threadIdx.x;

    int bc = (t < K) ? min(bcnt[t], BCAP) : 0;
    pre[t] = bc;
    __syncthreads();
    for (int off = 1; off < 256; off <<= 1) {
        int v = (t >= off) ? pre[t - off] : 0;
        __syncthreads();
        pre[t] += v;
        __syncthreads();
    }
    const int base_b = (b == 0) ? 0 : pre[b - 1];
    const int cnt_b  = pre[b] - base_b;
    if (b == K - 1 && t == 0) rowptr[N] = pre[K - 1];

    const int nlo = b << BIN_SHIFT;
    const int nhi = min(nlo + (1 << BIN_SHIFT), N);
    const int nn  = nhi - nlo;
    const int* te = tmpE + (size_t)b * BCAP;

    cur[t] = 0;
    cur[t + 256] = 0;
    __syncthreads();
    for (int i = t; i < cnt_b; i += 256) atomicAdd(&cur[te[i] & 511], 1);
    __syncthreads();

    int v0 = cur[2 * t], v1 = cur[2 * t + 1];
    ss[t] = v0 + v1;
    __syncthreads();
    for (int off = 1; off < 256; off <<= 1) {
        int v = (t >= off) ? ss[t - off] : 0;
        __syncthreads();
        ss[t] += v;
        __syncthreads();
    }
    int e0 = (t == 0) ? 0 : ss[t - 1];
    int e1 = e0 + v0;
    if (2 * t < nn)     rowptr[nlo + 2 * t]     = base_b + e0;
    if (2 * t + 1 < nn) rowptr[nlo + 2 * t + 1] = base_b + e1;
    cur[2 * t] = e0;
    cur[2 * t + 1] = e1;
    __syncthreads();

    for (int i = t; i < cnt_b; i += 256) {
        int v = te[i];
        int r = atomicAdd(&cur[v & 511], 1);
        colOff[base_b + r] = ((unsigned)v >> 9) << 8;
    }
}

// gemm: one 128-row tile of h = X @ W via split-bf16 MFMA; bf16 Hout + log2e-scaled fp32 alphas.
static __device__ void gemm_body(int bid, const float* __restrict__ X,
                                 const unsigned short* __restrict__ Wh,
                                 const unsigned short* __restrict__ Wl,
                                 const float* __restrict__ a_s,
                                 const float* __restrict__ a_d,
                                 unsigned short* __restrict__ Hout,
                                 float* __restrict__ asrc,
                                 float* __restrict__ adst,
                                 int N, unsigned short* hstage) {
    const int tid = threadIdx.x;
    const int wid = tid >> 6;
    const int l   = tid & 63;
    const int l15 = l & 15;
    const int lh  = l >> 4;
    const int waveRow = bid * 128 + wid * 32;
    if (waveRow >= N) return;

    f32x4 acc[2][8];
#pragma unroll
    for (int m = 0; m < 2; ++m)
#pragma unroll
        for (int f = 0; f < 8; ++f)
#pragma unroll
            for (int c = 0; c < 4; ++c) acc[m][f][c] = 0.f;

    const int r0 = waveRow + l15;
    const int r1 = waveRow + 16 + l15;
    const size_t xoff0 = (size_t)min(r0, N - 1) * 128;   // clamp: junk rows never stored
    const size_t xoff1 = (size_t)min(r1, N - 1) * 128;
    const int kb = lh * 8;

#pragma unroll
    for (int ks = 0; ks < 4; ++ks) {
        bf16x8 ah[2], al[2];
#pragma unroll
        for (int m = 0; m < 2; ++m) {
            const float* xp = X + (m ? xoff1 : xoff0) + ks * 32 + kb;
            float4 v0 = *(const float4*)xp;
            float4 v1 = *(const float4*)(xp + 4);
            float xs[8] = {v0.x, v0.y, v0.z, v0.w, v1.x, v1.y, v1.z, v1.w};
#pragma unroll
            for (int j = 0; j < 8; ++j) {
                unsigned short h = bf16r(xs[j]);
                float hf = __uint_as_float((unsigned)h << 16);
                ah[m][j] = (short)h;
                al[m][j] = (short)bf16r(xs[j] - hf);
            }
        }
        const unsigned short* wbh = Wh + ks * 4096 + l * 8;
        const unsigned short* wbl = Wl + ks * 4096 + l * 8;
#pragma unroll
        for (int f = 0; f < 8; ++f) {
            bf16x8 wh = *(const bf16x8*)(wbh + f * 512);
            bf16x8 wl = *(const bf16x8*)(wbl + f * 512);
#pragma unroll
            for (int m = 0; m < 2; ++m) {
                acc[m][f] = __builtin_amdgcn_mfma_f32_16x16x32_bf16(ah[m], wh, acc[m][f], 0, 0, 0);
                acc[m][f] = __builtin_amdgcn_mfma_f32_16x16x32_bf16(al[m], wh, acc[m][f], 0, 0, 0);
                acc[m][f] = __builtin_amdgcn_mfma_f32_16x16x32_bf16(ah[m], wl, acc[m][f], 0, 0, 0);
            }
        }
    }

    float asf[8], adf[8];
#pragma unroll
    for (int f = 0; f < 8; ++f) {
        asf[f] = a_s[f * 16 + l15];
        adf[f] = a_d[f * 16 + l15];
    }
    const int q = l15;
#pragma unroll
    for (int m = 0; m < 2; ++m) {
#pragma unroll
        for (int r = 0; r < 4; ++r) {
            float ps[4] = {0.f, 0.f, 0.f, 0.f};
            float pd[4] = {0.f, 0.f, 0.f, 0.f};
#pragma unroll
            for (int f = 0; f < 8; ++f) {
                float v = acc[m][f][r];
                ps[f >> 1] = fmaf(v, asf[f], ps[f >> 1]);
                pd[f >> 1] = fmaf(v, adf[f], pd[f >> 1]);
                hstage[((wid * 32) + m * 16 + lh * 4 + r) * 132 + f * 16 + l15] = bf16r(v);
            }
#pragma unroll
            for (int mask = 1; mask < 16; mask <<= 1) {
#pragma unroll
                for (int h = 0; h < 4; ++h) {
                    ps[h] += __shfl_xor(ps[h], mask);
                    pd[h] += __shfl_xor(pd[h], mask);
                }
            }
            int row = waveRow + m * 16 + lh * 4 + r;
            if (q < 8 && row < N) {
                float v0 = (q & 1) ? ps[1] : ps[0];
                float v1 = (q & 1) ? ps[3] : ps[2];
                float vs = (q & 2) ? v1 : v0;
                float w0 = (q & 1) ? pd[1] : pd[0];
                float w1 = (q & 1) ? pd[3] : pd[2];
                float vd = (q & 2) ? w1 : w0;
                // pre-scale by log2(e): aggregate uses native exp2 (lrelu is pos-homogeneous)
                if (q < 4) asrc[row * 4 + q] = vs * LOG2E;
                else       adst[row * 4 + (q - 4)] = vd * LOG2E;
            }
        }
    }

    // coalesced bf16 store: 16 lanes cover one 256B h-row, 4 rows per iteration
#pragma unroll
    for (int it = 0; it < 8; ++it) {
        int row = it * 4 + lh;
        const unsigned short* hp = hstage + ((wid * 32) + row) * 132 + l15 * 8;
        uint2 aa = *(const uint2*)hp;
        uint2 bb = *(const uint2*)(hp + 4);
        int grow = waveRow + row;
        if (grow < N) {
            uint4 o;
            o.x = aa.x; o.y = aa.y; o.z = bb.x; o.w = bb.y;
            *(uint4*)&Hout[(size_t)grow * 128 + l15 * 8] = o;
        }
    }
}

// aggregate: 4 nodes per block (one wave each); all-8-wide predicated chunks (tail lanes w=0 exact).
static __device__ void agg_body(int grp, const unsigned short* __restrict__ Hbuf,
                                const float* __restrict__ asrc, const float* __restrict__ adst,
                                const int* __restrict__ rowptr, const int* __restrict__ colOff,
                                const float* __restrict__ bias, float* __restrict__ out, int N) {
    const int wid  = threadIdx.x >> 6;
    const int lane = threadIdx.x & 63;
    const int n = grp * 4 + wid;
    if (n >= N) return;
    const int c0 = lane * 2;
    const int head = c0 >> 5;
    const float adh = adst[n * 4 + head];
    const char* Hb = (const char*)Hbuf;
    const char* As = (const char*)asrc;
    const int hoff = c0 * 2;
    const int aoff = head * 4;

    int b = __builtin_amdgcn_readfirstlane(rowptr[n]);
    int e = __builtin_amdgcn_readfirstlane(rowptr[n + 1]);
    float acc0 = 0.f, acc1 = 0.f, sw = 0.f;
    for (int p = b; p < e; p += 8) {
        int off[8];
#pragma unroll
        for (int j = 0; j < 8; ++j) off[j] = colOff[min(p + j, e - 1)];
        float a[8];
#pragma unroll
        for (int j = 0; j < 8; ++j) a[j] = *(const float*)(As + (off[j] >> 4) + aoff);
        unsigned hu[8];
#pragma unroll
        for (int j = 0; j < 8; ++j) hu[j] = *(const unsigned*)(Hb + off[j] + hoff);
#pragma unroll
        for (int j = 0; j < 8; ++j) {
            float x = a[j] + adh;
            float w = (p + j < e) ? EXP2(fmaxf(x, NEG_SLOPE * x)) : 0.f;
            sw += w;
            acc0 = fmaf(w, bfu_lo(hu[j]), acc0);
            acc1 = fmaf(w, bfu_hi(hu[j]), acc1);
        }
    }
    float inv = 1.f / sw;
    float o0 = fmaxf(acc0 * inv + bias[c0], 0.f);
    float o1 = fmaxf(acc1 * inv + bias[c0 + 1], 0.f);
    *(float2*)&out[(size_t)n * 128 + c0] = make_float2(o0, o1);
}

// ================= kernels =================

// fused: W-prep blocks [0,128) run concurrently with bin blocks [128, 128+nchunks).
// Independent work; bcnt is pre-zeroed by a memset dispatch so no cross-block ordering needed.
__global__ __launch_bounds__(256) void prep1_k(const float* __restrict__ W1, const float* __restrict__ W2,
                                               unsigned short* __restrict__ Wh1, unsigned short* __restrict__ Wl1,
                                               unsigned short* __restrict__ Wh2, unsigned short* __restrict__ Wl2,
                                               const int* __restrict__ srcI, const int* __restrict__ dstI,
                                               int E, int N, int K, int* __restrict__ bcnt,
                                               int* __restrict__ tmpE) {
    __shared__ int hist[256], lbase[256], lstart[256], curA[256], sc[256];
    __shared__ int staged[4096];
    __shared__ unsigned char bs[4096];
    const int bid = blockIdx.x;
    if (bid < 128) {
        int t = bid * 256 + threadIdx.x;
        wprep_elem(t, W1, W2, Wh1, Wl1, Wh2, Wl2);
    } else {
        bin_body(bid - 128, srcI, dstI, E, N, K, bcnt, tmpE,
                 hist, lbase, lstart, curA, sc, staged, bs);
    }
}

// fused: scatter blocks [0,K) overlap with gemm layer-1 blocks [K, K+gemmTiles).
// scatter depends on bin (previous dispatch); gemm depends on W-prep (previous dispatch).
// LDS is a union: scatter uses the first 4KB of gemm's 33.8KB hstage buffer.
__global__ __launch_bounds__(256) void gemm1_scatter_k(const int* __restrict__ tmpE,
                                                       const int* __restrict__ bcnt,
                                                       int* __restrict__ rowptr,
                                                       int* __restrict__ colOff,
                                                       int K,
                                                       const float* __restrict__ X,
                                                       const unsigned short* __restrict__ Wh,
                                                       const unsigned short* __restrict__ Wl,
                                                       const float* __restrict__ a_s,
                                                       const float* __restrict__ a_d,
                                                       unsigned short* __restrict__ Hout,
                                                       float* __restrict__ asrc,
                                                       float* __restrict__ adst,
                                                       int N) {
    __shared__ __align__(16) unsigned short smem[4 * 32 * 132];   // 33792 B
    const int bid = blockIdx.x;
    if (bid < K) {
        int* pre = (int*)smem;          // 256 ints
        int* cur = pre + 256;           // 512 ints
        int* ss  = cur + 512;           // 256 ints  (4KB total < 33792B)
        scatter_body(bid, tmpE, bcnt, rowptr, colOff, N, K, pre, cur, ss);
    } else {
        gemm_body(bid - K, X, Wh, Wl, a_s, a_d, Hout, asrc, adst, N, smem);
    }
}

__global__ __launch_bounds__(256) void gemm_mfma_k(const float* __restrict__ X,
                                                   const unsigned short* __restrict__ Wh,
                                                   const unsigned short* __restrict__ Wl,
                                                   const float* __restrict__ a_s,
                                                   const float* __restrict__ a_d,
                                                   unsigned short* __restrict__ Hout,
                                                   float* __restrict__ asrc,
                                                   float* __restrict__ adst,
                                                   int N) {
    __shared__ __align__(16) unsigned short hstage[4 * 32 * 132];
    gemm_body(blockIdx.x, X, Wh, Wl, a_s, a_d, Hout, asrc, adst, N, hstage);
}

__global__ __launch_bounds__(256) void aggregate_k(const unsigned short* __restrict__ Hbuf,
                                                   const float* __restrict__ asrc,
                                                   const float* __restrict__ adst,
                                                   const int* __restrict__ rowptr,
                                                   const int* __restrict__ colOff,
                                                   const float* __restrict__ bias,
                                                   float* __restrict__ out, int N) {
    agg_body(blockIdx.x, Hbuf, asrc, adst, rowptr, colOff, bias, out, N);
}

// ================= launch: 5 kernel dispatches + 1 memset =================

extern "C" void kernel_launch(void* const* d_in, const int* in_sizes, int n_in,
                              void* d_out, int out_size, void* d_ws, size_t ws_size,
                              hipStream_t stream) {
    const float* X   = (const float*)d_in[0];
    const int*   EI  = (const int*)d_in[1];
    const float* W1  = (const float*)d_in[2];
    const float* as1 = (const float*)d_in[3];
    const float* ad1 = (const float*)d_in[4];
    const float* b1  = (const float*)d_in[5];
    const float* W2  = (const float*)d_in[6];
    const float* as2 = (const float*)d_in[7];
    const float* ad2 = (const float*)d_in[8];
    const float* b2  = (const float*)d_in[9];

    const int N = in_sizes[0] / 128;
    const int E = in_sizes[1] / 2;
    const int M = E + N;
    const int K = (N + (1 << BIN_SHIFT) - 1) >> BIN_SHIFT;   // <= 256 for N <= 131072
    const int* srcI = EI;
    const int* dstI = EI + E;

    char* w = (char*)d_ws;
    auto alloc = [&](size_t bytes) {
        char* p = w;
        w += (bytes + 255) & ~(size_t)255;
        return p;
    };
    unsigned short* Hbuf = (unsigned short*)alloc((size_t)N * 128 * 2);  // bf16, 256B rows
    float* asrc   = (float*)alloc((size_t)N * 4 * 4);
    float* adst   = (float*)alloc((size_t)N * 4 * 4);
    int*   rowptr = (int*)alloc((size_t)(N + 1) * 4);
    int*   colOff = (int*)alloc((size_t)M * 4);
    int*   tmpE   = (int*)alloc((size_t)K * BCAP * 4);       // packed (src<<9 | dst&511)
    int*   bcnt   = (int*)alloc(256 * 4);
    unsigned short* Wt1h = (unsigned short*)alloc(128 * 128 * 2);
    unsigned short* Wt1l = (unsigned short*)alloc(128 * 128 * 2);
    unsigned short* Wt2h = (unsigned short*)alloc(128 * 128 * 2);
    unsigned short* Wt2l = (unsigned short*)alloc(128 * 128 * 2);

    const int gemmTiles  = (N + 127) / 128;
    const int nodeGroups = (N + 3) / 4;
    const int nchunks    = (M + 4095) / 4096;
    float* out = (float*)d_out;

    // 0: zero bucket counters (tiny graph node; removes cross-block ordering need in prep1)
    hipMemsetAsync(bcnt, 0, 256 * 4, stream);
    // 1: W pre-split || edge binning (independent; fused grid partition)
    prep1_k<<<128 + nchunks, 256, 0, stream>>>(W1, W2, Wt1h, Wt1l, Wt2h, Wt2l,
                                               srcI, dstI, E, N, K, bcnt, tmpE);
    // 2: per-bucket CSR scatter || gemm layer 1 (independent; scatter hides under gemm)
    gemm1_scatter_k<<<K + gemmTiles, 256, 0, stream>>>(tmpE, bcnt, rowptr, colOff, K,
                                                       X, Wt1h, Wt1l, as1, ad1, Hbuf, asrc, adst, N);
    // 3: aggregate layer 1 (activation staged in d_out, fp32)
    aggregate_k<<<nodeGroups, 256, 0, stream>>>(Hbuf, asrc, adst, rowptr, colOff, b1, out, N);
    // 4: gemm layer 2
    gemm_mfma_k<<<gemmTiles, 256, 0, stream>>>(out, Wt2h, Wt2l, as2, ad2, Hbuf, asrc, adst, N);
    // 5: aggregate layer 2
    aggregate_k<<<nodeGroups, 256, 0, stream>>>(Hbuf, asrc, adst, rowptr, colOff, b2, out, N);
}

// Round 11
// 367.933 us; speedup vs baseline: 1.6911x; 1.1021x over previous
//
#include <hip/hip_runtime.h>
#include <cstdint>
#include <cstddef>

#define NEG_SLOPE 0.2f
#define BIN_SHIFT 9      // 512 nodes per bucket
#define BCAP 16384       // fixed tmpE capacity per bucket (expected ~8700, ~80 sigma margin)
#define LOG2E 1.4426950408889634f

typedef short bf16x8 __attribute__((ext_vector_type(8)));
typedef float f32x4 __attribute__((ext_vector_type(4)));

#if __has_builtin(__builtin_amdgcn_exp2f)
#define EXP2(x) __builtin_amdgcn_exp2f(x)
#else
#define EXP2(x) exp2f(x)
#endif

// fp32 -> bf16 RTNE
static __device__ __forceinline__ unsigned short bf16r(float f) {
    unsigned u = __float_as_uint(f);
    return (unsigned short)((u + 0x7fffu + ((u >> 16) & 1u)) >> 16);
}
static __device__ __forceinline__ float bfu_lo(unsigned u) { return __uint_as_float(u << 16); }
static __device__ __forceinline__ float bfu_hi(unsigned u) { return __uint_as_float(u & 0xffff0000u); }

// ---------------- W prep: bf16 hi/lo split into MFMA-fragment-contiguous layout + bcnt zero ----------------
// WB[ks][f][lane][8]: element (col=f*16+l15, k=ks*32+lh*8+j) at ((ks*8+f)*64 + lh*16+l15)*8 + j.
__global__ __launch_bounds__(256) void wprep_k(const float* __restrict__ W1, const float* __restrict__ W2,
                                               unsigned short* __restrict__ Wh1, unsigned short* __restrict__ Wl1,
                                               unsigned short* __restrict__ Wh2, unsigned short* __restrict__ Wl2,
                                               int* __restrict__ bcnt) {
    if (blockIdx.x == 0) bcnt[threadIdx.x] = 0;
    int t = blockIdx.x * 256 + threadIdx.x;       // grid 128 -> 32768 threads
    const float* W;
    unsigned short *Wh, *Wl;
    int idx;
    if (t < 16384) { W = W1; Wh = Wh1; Wl = Wl1; idx = t; }
    else           { W = W2; Wh = Wh2; Wl = Wl2; idx = t - 16384; }
    int c = idx >> 7;     // output col 0..127
    int k = idx & 127;    // input k 0..127
    float w = W[(size_t)k * 128 + c];
    unsigned short h = bf16r(w);
    float lo = w - __uint_as_float((unsigned)h << 16);
    int dst = (k >> 5) * 4096 + (c >> 4) * 512 + (((k >> 3) & 3) * 16 + (c & 15)) * 8 + (k & 7);
    Wh[dst] = h;
    Wl[dst] = bf16r(lo);
}

// ---------------- Phase A: bin edges into fixed-capacity dst buckets; LDS counting sort -> coalesced writes ----------------
// tmpE entry packed: (src << 9) | (dst & 511). Edge loads are int4-vectorized (4 edges per load,
// 8x16B instead of 32x4B per thread); only the boundary chunk takes the scalar fallback.
__global__ __launch_bounds__(256) void bin_k(const int* __restrict__ srcI, const int* __restrict__ dstI,
                                             int E, int N, int K, int* __restrict__ bcnt,
                                             int* __restrict__ tmpE) {
    __shared__ int hist[256];
    __shared__ int lbase[256];    // this block's allocated base within each bucket (bcnt atomic)
    __shared__ int lstart[256];   // exclusive prefix of hist (local slot range start per bucket)
    __shared__ int cur[256];      // local placement cursors
    __shared__ int sc[256];       // scan temp
    __shared__ int staged[4096];  // bucket-sorted packed entries (16 KB)
    __shared__ unsigned char bs[4096];  // bucket id per slot (4 KB)
    const int t = threadIdx.x;
    const int M = E + N;
    const int chunk0 = blockIdx.x * 4096;
    hist[t] = 0;
    __syncthreads();

    int pk[16], bk[16];
#pragma unroll
    for (int jj = 0; jj < 4; ++jj) {
        int ebase = chunk0 + (t + jj * 256) * 4;
        if (ebase + 4 <= E) {
            int4 s4 = *(const int4*)&srcI[ebase];
            int4 d4 = *(const int4*)&dstI[ebase];
            int ssv[4] = {s4.x, s4.y, s4.z, s4.w};
            int ddv[4] = {d4.x, d4.y, d4.z, d4.w};
#pragma unroll
            for (int j = 0; j < 4; ++j) {
                int q = jj * 4 + j;
                bk[q] = -1;
                if ((unsigned)ddv[j] < (unsigned)N && (unsigned)ssv[j] < (unsigned)N) {
                    bk[q] = ddv[j] >> BIN_SHIFT;
                    pk[q] = (ssv[j] << 9) | (ddv[j] & 511);
                    atomicAdd(&hist[bk[q]], 1);
                }
            }
        } else {
#pragma unroll
            for (int j = 0; j < 4; ++j) {
                int q = jj * 4 + j;
                int i = ebase + j;
                bk[q] = -1;
                if (i < M) {
                    int ss, dd;
                    if (i < E) { ss = srcI[i]; dd = dstI[i]; }
                    else       { ss = i - E;  dd = ss; }          // self-loops
                    if ((unsigned)dd < (unsigned)N && (unsigned)ss < (unsigned)N) {
                        bk[q] = dd >> BIN_SHIFT;
                        pk[q] = (ss << 9) | (dd & 511);
                        atomicAdd(&hist[bk[q]], 1);
                    }
                }
            }
        }
    }
    __syncthreads();
    const int h = hist[t];
    lbase[t] = (h > 0) ? atomicAdd(&bcnt[t], h) : 0;
    sc[t] = h;
    __syncthreads();
    for (int off = 1; off < 256; off <<= 1) {
        int v = (t >= off) ? sc[t - off] : 0;
        __syncthreads();
        sc[t] += v;
        __syncthreads();
    }
    lstart[t] = sc[t] - h;
    cur[t]    = sc[t] - h;
    __syncthreads();
#pragma unroll
    for (int j = 0; j < 16; ++j) {
        if (bk[j] >= 0) {
            int r = atomicAdd(&cur[bk[j]], 1);
            staged[r] = pk[j];
            bs[r] = (unsigned char)bk[j];
        }
    }
    const int total = sc[255];
    __syncthreads();
    // coalesced write-out: consecutive slots of one bucket -> consecutive global positions
    for (int s = t; s < total; s += 256) {
        int b = bs[s];
        int posInBucket = lbase[b] + (s - lstart[b]);
        if (posInBucket < BCAP) tmpE[(size_t)b * BCAP + posInBucket] = staged[s];
    }
}

// ---------------- Phase B: per-bucket local CSR build + scatter; colOff = src*256 (byte offset) ----------------
// te reads int4-vectorized in both passes (9 iterations instead of 34 per pass).
__global__ __launch_bounds__(256) void scatter_csr_k(const int* __restrict__ tmpE,
                                                     const int* __restrict__ bcnt,
                                                     int* __restrict__ rowptr,
                                                     int* __restrict__ colOff,
                                                     int N, int K) {
    __shared__ int pre[256];
    __shared__ int cur[512];
    __shared__ int ss[256];
    const int t = threadIdx.x;
    const int b = blockIdx.x;

    int bc = (t < K) ? min(bcnt[t], BCAP) : 0;
    pre[t] = bc;
    __syncthreads();
    for (int off = 1; off < 256; off <<= 1) {
        int v = (t >= off) ? pre[t - off] : 0;
        __syncthreads();
        pre[t] += v;
        __syncthreads();
    }
    const int base_b = (b == 0) ? 0 : pre[b - 1];
    const int cnt_b  = pre[b] - base_b;
    if (b == K - 1 && t == 0) rowptr[N] = pre[K - 1];

    const int nlo = b << BIN_SHIFT;
    const int nhi = min(nlo + (1 << BIN_SHIFT), N);
    const int nn  = nhi - nlo;
    const int* te = tmpE + (size_t)b * BCAP;   // 64KB-aligned slab: int4 loads are safe in-bounds

    cur[t] = 0;
    cur[t + 256] = 0;
    __syncthreads();
    for (int i0 = t * 4; i0 < cnt_b; i0 += 1024) {
        int4 v = *(const int4*)&te[i0];
        int vv[4] = {v.x, v.y, v.z, v.w};
#pragma unroll
        for (int j = 0; j < 4; ++j)
            if (i0 + j < cnt_b) atomicAdd(&cur[vv[j] & 511], 1);
    }
    __syncthreads();

    int v0 = cur[2 * t], v1 = cur[2 * t + 1];
    ss[t] = v0 + v1;
    __syncthreads();
    for (int off = 1; off < 256; off <<= 1) {
        int v = (t >= off) ? ss[t - off] : 0;
        __syncthreads();
        ss[t] += v;
        __syncthreads();
    }
    int e0 = (t == 0) ? 0 : ss[t - 1];
    int e1 = e0 + v0;
    if (2 * t < nn)     rowptr[nlo + 2 * t]     = base_b + e0;
    if (2 * t + 1 < nn) rowptr[nlo + 2 * t + 1] = base_b + e1;
    cur[2 * t] = e0;
    cur[2 * t + 1] = e1;
    __syncthreads();

    for (int i0 = t * 4; i0 < cnt_b; i0 += 1024) {
        int4 v = *(const int4*)&te[i0];
        int vv[4] = {v.x, v.y, v.z, v.w};
#pragma unroll
        for (int j = 0; j < 4; ++j) {
            if (i0 + j < cnt_b) {
                int r = atomicAdd(&cur[vv[j] & 511], 1);
                colOff[base_b + r] = ((unsigned)vv[j] >> 9) << 8;   // byte offset of src's 256B Hbuf row
            }
        }
    }
}

// ---------------- h = X @ W via split-bf16 MFMA; bf16 Hout + log2e-scaled fp32 alphas ----------------
// X@W ~= Xh@Wh + Xl@Wh + Xh@Wl (dropped Xl@Wl ~2^-18) -> fp32-grade accuracy.
// B-fragments from the WB contiguous layout: one 1KB coalesced segment per (ks,f) wave-load.
__global__ __launch_bounds__(256) void gemm_mfma_k(const float* __restrict__ X,
                                                   const unsigned short* __restrict__ Wh,
                                                   const unsigned short* __restrict__ Wl,
                                                   const float* __restrict__ a_s,
                                                   const float* __restrict__ a_d,
                                                   unsigned short* __restrict__ Hout,
                                                   float* __restrict__ asrc,
                                                   float* __restrict__ adst,
                                                   int N) {
    __shared__ __align__(16) unsigned short hstage[4][32][132];  // +4 pad: conflict-light
    const int tid = threadIdx.x;
    const int wid = tid >> 6;
    const int l   = tid & 63;
    const int l15 = l & 15;
    const int lh  = l >> 4;
    const int waveRow = blockIdx.x * 128 + wid * 32;
    if (waveRow >= N) return;

    f32x4 acc[2][8];
#pragma unroll
    for (int m = 0; m < 2; ++m)
#pragma unroll
        for (int f = 0; f < 8; ++f)
#pragma unroll
            for (int c = 0; c < 4; ++c) acc[m][f][c] = 0.f;

    const int r0 = waveRow + l15;
    const int r1 = waveRow + 16 + l15;
    const size_t xoff0 = (size_t)min(r0, N - 1) * 128;   // clamp: junk rows never stored
    const size_t xoff1 = (size_t)min(r1, N - 1) * 128;
    const int kb = lh * 8;

#pragma unroll
    for (int ks = 0; ks < 4; ++ks) {
        bf16x8 ah[2], al[2];
#pragma unroll
        for (int m = 0; m < 2; ++m) {
            const float* xp = X + (m ? xoff1 : xoff0) + ks * 32 + kb;
            float4 v0 = *(const float4*)xp;
            float4 v1 = *(const float4*)(xp + 4);
            float xs[8] = {v0.x, v0.y, v0.z, v0.w, v1.x, v1.y, v1.z, v1.w};
#pragma unroll
            for (int j = 0; j < 8; ++j) {
                unsigned short h = bf16r(xs[j]);
                float hf = __uint_as_float((unsigned)h << 16);
                ah[m][j] = (short)h;
                al[m][j] = (short)bf16r(xs[j] - hf);
            }
        }
        const unsigned short* wbh = Wh + ks * 4096 + l * 8;
        const unsigned short* wbl = Wl + ks * 4096 + l * 8;
#pragma unroll
        for (int f = 0; f < 8; ++f) {
            bf16x8 wh = *(const bf16x8*)(wbh + f * 512);
            bf16x8 wl = *(const bf16x8*)(wbl + f * 512);
#pragma unroll
            for (int m = 0; m < 2; ++m) {
                acc[m][f] = __builtin_amdgcn_mfma_f32_16x16x32_bf16(ah[m], wh, acc[m][f], 0, 0, 0);
                acc[m][f] = __builtin_amdgcn_mfma_f32_16x16x32_bf16(al[m], wh, acc[m][f], 0, 0, 0);
                acc[m][f] = __builtin_amdgcn_mfma_f32_16x16x32_bf16(ah[m], wl, acc[m][f], 0, 0, 0);
            }
        }
    }

    float asf[8], adf[8];
#pragma unroll
    for (int f = 0; f < 8; ++f) {
        asf[f] = a_s[f * 16 + l15];
        adf[f] = a_d[f * 16 + l15];
    }
    const int q = l15;
#pragma unroll
    for (int m = 0; m < 2; ++m) {
#pragma unroll
        for (int r = 0; r < 4; ++r) {
            float ps[4] = {0.f, 0.f, 0.f, 0.f};
            float pd[4] = {0.f, 0.f, 0.f, 0.f};
#pragma unroll
            for (int f = 0; f < 8; ++f) {
                float v = acc[m][f][r];
                ps[f >> 1] = fmaf(v, asf[f], ps[f >> 1]);
                pd[f >> 1] = fmaf(v, adf[f], pd[f >> 1]);
                hstage[wid][m * 16 + lh * 4 + r][f * 16 + l15] = bf16r(v);
            }
#pragma unroll
            for (int mask = 1; mask < 16; mask <<= 1) {
#pragma unroll
                for (int h = 0; h < 4; ++h) {
                    ps[h] += __shfl_xor(ps[h], mask);
                    pd[h] += __shfl_xor(pd[h], mask);
                }
            }
            int row = waveRow + m * 16 + lh * 4 + r;
            if (q < 8 && row < N) {
                float v0 = (q & 1) ? ps[1] : ps[0];
                float v1 = (q & 1) ? ps[3] : ps[2];
                float vs = (q & 2) ? v1 : v0;
                float w0 = (q & 1) ? pd[1] : pd[0];
                float w1 = (q & 1) ? pd[3] : pd[2];
                float vd = (q & 2) ? w1 : w0;
                // pre-scale by log2(e): aggregate uses native exp2 (lrelu is pos-homogeneous)
                if (q < 4) asrc[row * 4 + q] = vs * LOG2E;
                else       adst[row * 4 + (q - 4)] = vd * LOG2E;
            }
        }
    }

    // coalesced bf16 store: 16 lanes cover one 256B h-row, 4 rows per iteration
#pragma unroll
    for (int it = 0; it < 8; ++it) {
        int row = it * 4 + lh;
        const unsigned short* hp = &hstage[wid][row][l15 * 8];
        uint2 aa = *(const uint2*)hp;
        uint2 bb = *(const uint2*)(hp + 4);
        int grow = waveRow + row;
        if (grow < N) {
            uint4 o;
            o.x = aa.x; o.y = aa.y; o.z = bb.x; o.w = bb.y;
            *(uint4*)&Hout[(size_t)grow * 128 + l15 * 8] = o;
        }
    }
}

// ---------------- aggregation: one wave per dst node; all-8-wide predicated chunks (no serial tail) ----------------
// w = exp2(lrelu(asrc'+adst')) with alphas pre-scaled by log2e == exp(lrelu(asrc+adst)).
// Invalid lanes in the last chunk read edge e-1 (valid memory) with w forced to exact 0:
// fmaf(0,h,acc)==acc and sw+=0 are bit-exact, so output matches the serial-tail version.
__global__ __launch_bounds__(256) void aggregate_k(const unsigned short* __restrict__ Hbuf,
                                                   const float* __restrict__ asrc,
                                                   const float* __restrict__ adst,
                                                   const int* __restrict__ rowptr,
                                                   const int* __restrict__ colOff,
                                                   const float* __restrict__ bias,
                                                   float* __restrict__ out, int N) {
    int wave = (blockIdx.x * 256 + threadIdx.x) >> 6;
    int lane = threadIdx.x & 63;
    if (wave >= N) return;
    const int n = wave;
    const int c0 = lane * 2;
    const int head = c0 >> 5;
    const float adh = adst[n * 4 + head];
    const char* Hb = (const char*)Hbuf;
    const char* As = (const char*)asrc;
    const int hoff = c0 * 2;            // byte offset of this lane's h dword in a 256B row
    const int aoff = head * 4;

    int b = __builtin_amdgcn_readfirstlane(rowptr[n]);
    int e = __builtin_amdgcn_readfirstlane(rowptr[n + 1]);
    float acc0 = 0.f, acc1 = 0.f, sw = 0.f;
    for (int p = b; p < e; p += 8) {
        int off[8];
#pragma unroll
        for (int j = 0; j < 8; ++j) off[j] = colOff[min(p + j, e - 1)];
        float a[8];
#pragma unroll
        for (int j = 0; j < 8; ++j) a[j] = *(const float*)(As + (off[j] >> 4) + aoff);
        unsigned hu[8];
#pragma unroll
        for (int j = 0; j < 8; ++j) hu[j] = *(const unsigned*)(Hb + off[j] + hoff);
#pragma unroll
        for (int j = 0; j < 8; ++j) {
            float x = a[j] + adh;
            float w = (p + j < e) ? EXP2(fmaxf(x, NEG_SLOPE * x)) : 0.f;
            sw += w;
            acc0 = fmaf(w, bfu_lo(hu[j]), acc0);
            acc1 = fmaf(w, bfu_hi(hu[j]), acc1);
        }
    }
    float inv = 1.f / sw;
    float o0 = fmaxf(acc0 * inv + bias[c0], 0.f);
    float o1 = fmaxf(acc1 * inv + bias[c0 + 1], 0.f);
    *(float2*)&out[(size_t)n * 128 + c0] = make_float2(o0, o1);
}

// ---------------- launch: 7 dispatches (R8-proven structure) ----------------

extern "C" void kernel_launch(void* const* d_in, const int* in_sizes, int n_in,
                              void* d_out, int out_size, void* d_ws, size_t ws_size,
                              hipStream_t stream) {
    const float* X   = (const float*)d_in[0];
    const int*   EI  = (const int*)d_in[1];
    const float* W1  = (const float*)d_in[2];
    const float* as1 = (const float*)d_in[3];
    const float* ad1 = (const float*)d_in[4];
    const float* b1  = (const float*)d_in[5];
    const float* W2  = (const float*)d_in[6];
    const float* as2 = (const float*)d_in[7];
    const float* ad2 = (const float*)d_in[8];
    const float* b2  = (const float*)d_in[9];

    const int N = in_sizes[0] / 128;
    const int E = in_sizes[1] / 2;
    const int M = E + N;
    const int K = (N + (1 << BIN_SHIFT) - 1) >> BIN_SHIFT;   // <= 256 for N <= 131072
    const int* srcI = EI;
    const int* dstI = EI + E;

    char* w = (char*)d_ws;
    auto alloc = [&](size_t bytes) {
        char* p = w;
        w += (bytes + 255) & ~(size_t)255;
        return p;
    };
    unsigned short* Hbuf = (unsigned short*)alloc((size_t)N * 128 * 2);  // bf16, 256B rows
    float* asrc   = (float*)alloc((size_t)N * 4 * 4);
    float* adst   = (float*)alloc((size_t)N * 4 * 4);
    int*   rowptr = (int*)alloc((size_t)(N + 1) * 4);
    int*   colOff = (int*)alloc((size_t)M * 4);
    int*   tmpE   = (int*)alloc((size_t)K * BCAP * 4);       // packed (src<<9 | dst&511)
    int*   bcnt   = (int*)alloc(256 * 4);
    unsigned short* Wt1h = (unsigned short*)alloc(128 * 128 * 2);
    unsigned short* Wt1l = (unsigned short*)alloc(128 * 128 * 2);
    unsigned short* Wt2h = (unsigned short*)alloc(128 * 128 * 2);
    unsigned short* Wt2l = (unsigned short*)alloc(128 * 128 * 2);

    const int gemmBlocks = (N + 127) / 128;
    float* out = (float*)d_out;

    // 1: W pre-split (fragment-contiguous layout) + bcnt zeroing
    wprep_k<<<128, 256, 0, stream>>>(W1, W2, Wt1h, Wt1l, Wt2h, Wt2l, bcnt);
    // 2: bin edges into buckets (LDS counting sort; int4-vectorized edge loads)
    bin_k<<<(M + 4095) / 4096, 256, 0, stream>>>(srcI, dstI, E, N, K, bcnt, tmpE);
    // 3: per-bucket CSR build + scatter (int4-vectorized te reads)
    scatter_csr_k<<<K, 256, 0, stream>>>(tmpE, bcnt, rowptr, colOff, N, K);
    // 4: gemm layer 1 (activation staged in d_out, fp32)
    gemm_mfma_k<<<gemmBlocks, 256, 0, stream>>>(X, Wt1h, Wt1l, as1, ad1, Hbuf, asrc, adst, N);
    // 5: aggregate layer 1
    aggregate_k<<<((size_t)N * 64 + 255) / 256, 256, 0, stream>>>(Hbuf, asrc, adst, rowptr, colOff, b1, out, N);
    // 6: gemm layer 2
    gemm_mfma_k<<<gemmBlocks, 256, 0, stream>>>(out, Wt2h, Wt2l, as2, ad2, Hbuf, asrc, adst, N);
    // 7: aggregate layer 2
    aggregate_k<<<((size_t)N * 64 + 255) / 256, 256, 0, stream>>>(Hbuf, asrc, adst, rowptr, colOff, b2, out, N);
}